// Round 4
// baseline (81.202 us; speedup 1.0000x reference)
//
#include <hip/hip_runtime.h>

// VQC 12-qubit statevector, batch=1024.
// THICK WAVES: one block = 2 waves = TWO batch elements. Each wave holds
// 32 regs (half-state) of elem0 AND elem1 -> 2 independent instruction
// streams per wave (ILP covers latency; 1 wave/SIMD). theta-trig and the
// Gray-code Z chain are batch-invariant -> computed once, applied to both.
// Flat index i (12 bits), qubit q <-> bit (11-q).
// Layout A: b11=w(q0), b10..b6=reg(q1..q5), b5..b0=lane(q6..q11)
// Layout B: b11=w(q0), b10..b5=lane(q1..q6), b4..b0=reg(q7..q11)
// Per layer: Y q1..5 in-reg [A]; A->B (wave-local, fuses Y_q6, NO internal
// barrier); Y q7..11 in-reg [B]; fused Z (all 12); B->A (block-wide, fuses
// CNOT Gray perm x=y^(y>>1) + next layer's Y_q0). Layer-0 Y_q0 folded into
// closed-form encoding; last layer's Zs are no-ops for |amp|^2 readout.

#define PI_F 3.14159265358979323846f
#define NR 32
#define PAD 66   // even: keeps b128 partner-pairs 16B-aligned

__device__ __forceinline__ float2 cmul(float2 a, float2 b) {
    return make_float2(a.x*b.x - a.y*b.y, a.x*b.y + a.y*b.x);
}
__device__ __forceinline__ float2 cmulc(float2 a, float2 b) {  // a * conj(b)
    return make_float2(a.x*b.x + a.y*b.y, a.y*b.x - a.x*b.y);
}

template<int RB>
__device__ __forceinline__ void ypow_reg(float2 (&a)[NR], float c, float s) {
    #pragma unroll
    for (int r0 = 0; r0 < NR; ++r0) {
        if ((r0 >> RB) & 1) continue;
        const int r1 = r0 | (1 << RB);
        float2 a0 = a[r0], a1 = a[r1];
        a[r0] = make_float2(c*a0.x - s*a1.x, c*a0.y - s*a1.y);
        a[r1] = make_float2(s*a0.x + c*a1.x, s*a0.y + c*a1.y);
    }
}

// A->B transpose fusing Y_q6. Wave-local: caller provides ONE pre-barrier;
// write->read ordering within the wave is guaranteed by in-order LDS.
__device__ __forceinline__ void exchange_AB_nb(float2 (&a)[NR], float2* wb,
                                               int lane, float c6, float s6) {
    #pragma unroll
    for (int r = 0; r < NR; ++r)           // slot = [b10..b6 | b4..b0 | b5]
        wb[r * PAD + (lane & 31) * 2 + (lane >> 5)] = a[r];
    const int g = lane >> 1;
    const float k0 = (lane & 1) ? s6 : c6;
    const float k1 = (lane & 1) ? c6 : -s6;
    #pragma unroll
    for (int r = 0; r < NR; ++r) {
        float2 p0 = wb[g * PAD + r * 2];       // b5 = 0  (lane-pair broadcast)
        float2 p1 = wb[g * PAD + r * 2 + 1];   // b5 = 1
        a[r] = make_float2(k0*p0.x + k1*p1.x, k0*p0.y + k1*p1.y);
    }
}

// B->A transpose fusing CNOT-chain perm (new[y]=old[y^(y>>1)]) + next Y_q0.
__device__ __forceinline__ void exchange_BA(float2 (&a)[NR], float2* buf,
                                            int w, int lane, float c0, float s0) {
    __syncthreads();                       // prior reads (any elem) done
    const int p6w = lane ^ (w << 5);
    #pragma unroll
    for (int r = 0; r < NR; ++r)           // slot = p6*PAD + (x4..x0)*2 + x11
        buf[p6w * PAD + r * 2 + w] = a[r];
    __syncthreads();
    const float k0 = w ? s0 : c0;
    const float k1 = w ? c0 : -s0;
    #pragma unroll
    for (int rp = 0; rp < NR; ++rp) {
        const int ylow = (rp << 6) | lane;         // b10..b0 of output index
        const int t = ylow ^ (ylow >> 1);          // Gray inverse (11 bits)
        const int base = (t >> 5) * PAD + (t & 31) * 2;
        float2 p0 = buf[base];                     // input b11 = 0
        float2 p1 = buf[base + 1];                 // input b11 = 1
        a[rp] = make_float2(k0*p0.x + k1*p1.x, k0*p0.y + k1*p1.y);
    }
}

// Fused Z (all 12 qubits, layout B) applied to BOTH elements; the Gray-code
// running product `cur` is batch-invariant given (w,lane).
__device__ __forceinline__ void fused_z_B2(float2 (&a0)[NR], float2 (&a1)[NR],
                                           int w, int lane, const float* __restrict__ th) {
    float alpha = w ? th[1] : 0.0f;
    #pragma unroll
    for (int k = 0; k < 6; ++k)                 // lane bit k <-> q(6-k)
        alpha += ((lane >> k) & 1) ? th[2*(6-k)+1] : 0.0f;
    float2 zb; __sincosf(PI_F * alpha, &zb.y, &zb.x);
    float2 zq[5];
    #pragma unroll
    for (int j = 0; j < 5; ++j)                 // reg bit j <-> q(11-j)
        __sincosf(PI_F * th[2*(11-j)+1], &zq[j].y, &zq[j].x);
    float2 cur = zb;
    a0[0] = cmul(a0[0], cur);
    a1[0] = cmul(a1[0], cur);
    #pragma unroll
    for (int k = 1; k < NR; ++k) {
        const int bit = __builtin_ctz(k);
        const int g = k ^ (k >> 1);
        cur = ((g >> bit) & 1) ? cmul(cur, zq[bit]) : cmulc(cur, zq[bit]);
        a0[g] = cmul(a0[g], cur);
        a1[g] = cmul(a1[g], cur);
    }
}

// Closed-form encoding + layer-0 Y_q0, layout A.
__device__ __forceinline__ void encode_init(float2 (&a)[NR], int w, int lane,
                                            const float* __restrict__ x,
                                            float c0, float s0) {
    float phb = 0.0f;
    #pragma unroll
    for (int k = 0; k < 6; ++k)                 // lane bit k <-> q(11-k)
        phb += ((lane >> k) & 1) ? x[11 - k] : 0.0f;
    float2 cisb; __sincosf(PI_F * phb, &cisb.y, &cisb.x);
    float2 E;    __sincosf(PI_F * x[0], &E.y, &E.x);
    float2 Fw = w ? make_float2(s0 + c0 * E.x,  c0 * E.y)
                  : make_float2(c0 - s0 * E.x, -s0 * E.y);
    float2 g0 = cmul(Fw, cisb);
    g0.x *= 0.015625f; g0.y *= 0.015625f;       // 1/64
    float2 zr[5];
    #pragma unroll
    for (int j = 0; j < 5; ++j)                 // layout-A reg bit j <-> q(5-j)
        __sincosf(PI_F * x[5 - j], &zr[j].y, &zr[j].x);
    float2 cur = g0;
    a[0] = cur;
    #pragma unroll
    for (int k = 1; k < NR; ++k) {
        const int bit = __builtin_ctz(k);
        const int g = k ^ (k >> 1);
        cur = ((g >> bit) & 1) ? cmul(cur, zr[bit]) : cmulc(cur, zr[bit]);
        a[g] = cur;
    }
}

// Readout in layout B: b11=w(q0), lane bit k<->q(6-k), reg bit j<->q(11-j)
__device__ __forceinline__ void readout(const float2 (&a)[NR], int w, int lane,
                                        float* __restrict__ red) {
    float totalP = 0.0f;
    float D[5] = {0, 0, 0, 0, 0};
    #pragma unroll
    for (int r = 0; r < NR; ++r) {
        const float p = a[r].x * a[r].x + a[r].y * a[r].y;
        totalP += p;
        #pragma unroll
        for (int j = 0; j < 5; ++j)
            D[j] += ((r >> j) & 1) ? -p : p;
    }
    #pragma unroll
    for (int q = 0; q < 12; ++q) {
        float v;
        if (q == 0)       v = w ? -totalP : totalP;
        else if (q <= 6)  v = ((lane >> (6 - q)) & 1) ? -totalP : totalP;
        else              v = D[11 - q];
        #pragma unroll
        for (int off = 32; off >= 1; off >>= 1)
            v += __shfl_xor(v, off, 64);
        if (lane == 0) red[w * 12 + q] = v;
    }
}

__global__ __launch_bounds__(128) void vqc_kernel(
    const float* __restrict__ inputs,   // [1024,12]
    const float* __restrict__ thetas,   // [72] = [3][12][2]
    float* __restrict__ out)            // [1024,12]
{
    __shared__ __align__(16) float2 buf[64 * PAD];   // 33,792 B, time-shared
    __shared__ float redBuf[2][24];

    const int b0 = blockIdx.x * 2;
    const int tid = threadIdx.x;
    const int w = tid >> 6;
    const int lane = tid & 63;
    const float* x0 = inputs + b0 * 12;
    const float* x1 = x0 + 12;

    float2 a0[NR], a1[NR];

    float s00, c00; __sincosf(0.5f * PI_F * thetas[0], &s00, &c00);
    encode_init(a0, w, lane, x0, c00, s00);
    encode_init(a1, w, lane, x1, c00, s00);

    #pragma unroll 1
    for (int l = 0; l < 3; ++l) {
        const float* th = thetas + l * 24;
        float yc[12], ys[12];
        #pragma unroll
        for (int q = 0; q < 12; ++q)
            __sincosf(0.5f * PI_F * th[2 * q], &ys[q], &yc[q]);

        // Y q1..q5 in-reg (layout A), both elements
        ypow_reg<4>(a0, yc[1], ys[1]); ypow_reg<4>(a1, yc[1], ys[1]);
        ypow_reg<3>(a0, yc[2], ys[2]); ypow_reg<3>(a1, yc[2], ys[2]);
        ypow_reg<2>(a0, yc[3], ys[3]); ypow_reg<2>(a1, yc[3], ys[3]);
        ypow_reg<1>(a0, yc[4], ys[4]); ypow_reg<1>(a1, yc[4], ys[4]);
        ypow_reg<0>(a0, yc[5], ys[5]); ypow_reg<0>(a1, yc[5], ys[5]);

        // A->B (wave-local). One barrier separates previous block-wide reads
        // from these writes; elem1 reuses the wave's half after elem0 (in-order LDS).
        __syncthreads();
        exchange_AB_nb(a0, buf + w * (NR * PAD), lane, yc[6], ys[6]);
        exchange_AB_nb(a1, buf + w * (NR * PAD), lane, yc[6], ys[6]);

        // Y q7..q11 in-reg (layout B)
        ypow_reg<4>(a0, yc[7],  ys[7]);  ypow_reg<4>(a1, yc[7],  ys[7]);
        ypow_reg<3>(a0, yc[8],  ys[8]);  ypow_reg<3>(a1, yc[8],  ys[8]);
        ypow_reg<2>(a0, yc[9],  ys[9]);  ypow_reg<2>(a1, yc[9],  ys[9]);
        ypow_reg<1>(a0, yc[10], ys[10]); ypow_reg<1>(a1, yc[10], ys[10]);
        ypow_reg<0>(a0, yc[11], ys[11]); ypow_reg<0>(a1, yc[11], ys[11]);

        if (l < 2) {
            fused_z_B2(a0, a1, w, lane, th);
            float sn, cn; __sincosf(0.5f * PI_F * th[24], &sn, &cn);  // next layer q0
            exchange_BA(a0, buf, w, lane, cn, sn);
            exchange_BA(a1, buf, w, lane, cn, sn);
        }
        // Layer 2: Zs are diagonal -> no effect on |amp|^2 readout; skipped.
    }

    readout(a0, w, lane, redBuf[0]);
    readout(a1, w, lane, redBuf[1]);
    __syncthreads();
    if (tid < 24) {
        const int e = tid / 12, q = tid - e * 12;
        out[(b0 + e) * 12 + q] = redBuf[e][q] + redBuf[e][12 + q];
    }
}

extern "C" void kernel_launch(void* const* d_in, const int* in_sizes, int n_in,
                              void* d_out, int out_size, void* d_ws, size_t ws_size,
                              hipStream_t stream) {
    const float* inputs = (const float*)d_in[0];   // [1024,12] f32
    const float* thetas = (const float*)d_in[1];   // [72] f32
    float* out = (float*)d_out;                    // [1024,12] f32
    vqc_kernel<<<dim3(512), dim3(128), 0, stream>>>(inputs, thetas, out);
}